// Round 9
// baseline (1153.113 us; speedup 1.0000x reference)
//
#include <hip/hip_runtime.h>
#include <hip/hip_cooperative_groups.h>
#include <stdint.h>

namespace cg = cooperative_groups;

// ---------------------------------------------------------------------------
// d128snn_delays, round 9: rank-4 Chebyshev DCLS + FIR-as-GEMM (BK=64),
// all 9 phases in ONE cooperative kernel with grid.sync() between phases.
// R9 = R8 with the BN coverage bug fixed: Y has 12800 rows x 32 uint4 groups
// = 409600 items (R8 looped to 51200 -> 7/8 of rows un-normalized, absmax 10.7
// in BOTH coop and fallback paths). Fallback: R7 multi-dispatch (201 us).
// ---------------------------------------------------------------------------

#define T_LEN 100
#define B_SZ  128
#define M_ROWS 12800
#define R_RANK 4
#define K_FIR 448
#define BN_ITEMS 409600   // 12800 rows * (256 ch / 8 per uint4)

typedef __bf16 v8bf __attribute__((ext_vector_type(8)));
typedef float  v4f  __attribute__((ext_vector_type(4)));
typedef unsigned int uint32;
typedef unsigned short ushort_t;

// PHI[tau][r] = exp(-u^2/2) * T_r(u), u = (tau-12)/12  (Chebyshev basis)
struct PhiT { float v[25][R_RANK]; };
constexpr double cexp_(double x) {
  double s = 1.0, t = 1.0;
  for (int n = 1; n < 30; ++n) { t = t * x / n; s += t; }
  return s;
}
constexpr PhiT make_phi() {
  PhiT P{};
  for (int tau = 0; tau < 25; ++tau) {
    double u = (tau - 12) / 12.0;
    double g = cexp_(-0.5 * u * u);
    double T0 = 1.0, T1 = u;
    P.v[tau][0] = (float)(g * T0);
    P.v[tau][1] = (float)(g * T1);
    for (int r = 2; r < R_RANK; ++r) {
      double T2 = 2.0 * u * T1 - T0;
      P.v[tau][r] = (float)(g * T2);
      T0 = T1; T1 = T2;
    }
  }
  return P;
}
constexpr PhiT PHI = make_phi();

__device__ __forceinline__ void gl_lds16(const void* g, void* l) {
  __builtin_amdgcn_global_load_lds(
      (const __attribute__((address_space(1))) char*)g,
      (__attribute__((address_space(3))) char*)l, 16, 0, 0);
}

// ---------------------------------------------------------------------------
// Phase bodies (shared by mega-kernel and fallback wrappers)
// ---------------------------------------------------------------------------
__device__ __forceinline__ void build_wr_body(
    const float* __restrict__ W, const float* __restrict__ P,
    __bf16* __restrict__ Wr, int CIN, int CINP, int COUT, int COUTP, int o) {
  for (int i = threadIdx.x; i < CINP; i += blockDim.x) {
    bool valid = (o < COUT) && (i < CIN);
    float w = valid ? W[(size_t)o * CIN + i] : 0.f;
    float p = valid ? P[(size_t)o * CIN + i] : 0.f;
    float S = 0.f;
#pragma unroll
    for (int l = 0; l < 25; ++l) {
      float d = ((float)(l - 12) - p) * (1.f / 12.f);
      S += expf(-0.5f * d * d);
    }
    float v = p * (1.f / 12.f);
    float g = w * expf(-0.5f * v * v) / (S + 1e-7f);
    float h = 0.5f * v, hh = h * h;
    float pw = 1.f;  // h^r / r!
#pragma unroll
    for (int r = 0; r < R_RANK; ++r) {
      float term = pw, sum = pw;
#pragma unroll
      for (int m = 1; m <= 6; ++m) {
        term *= hh / (float)(m * (m + r));
        sum += term;
      }
      float c = g * ((r == 0) ? 1.f : 2.f) * sum;
      Wr[((size_t)r * COUTP + o) * CINP + i] = (__bf16)c;
      pw *= h / (float)(r + 1);
    }
  }
}

#define SETUP_JOBS 13541
__device__ __forceinline__ void setup_body(
    int blk, const float* x,
    const float* W1, const float* P1, const float* W2, const float* P2,
    const float* W3, const float* P3, __bf16* Xb, __bf16* Wr1, __bf16* Wr2,
    __bf16* Wr3, __bf16* Af, float* stats) {
  if (blk < 256) { build_wr_body(W1, P1, Wr1, 700, 704, 256, 256, blk); return; }
  blk -= 256;
  if (blk < 256) { build_wr_body(W2, P2, Wr2, 256, 256, 256, 256, blk); return; }
  blk -= 256;
  if (blk < 32) { build_wr_body(W3, P3, Wr3, 256, 256, 20, 32, blk); return; }
  blk -= 32;
  if (blk < 196) {  // Afir (112 x 448)
    int idx = blk * 256 + threadIdx.x;
    if (idx < 112 * 448) {
      int t = idx / 448, k = idx - t * 448;
      float v = 0.f;
      if (t < 100 && k < 400) {
        int r = k / 100, s = k - r * 100;
        int tau = s - t + 24;
        if (tau >= 0 && tau < 25) v = PHI.v[tau][r];
      }
      Af[idx] = (__bf16)v;
    }
    return;
  }
  blk -= 196;
  if (blk < 12800) {  // x (B,T,700) f32 -> Xb (T,B,704) bf16
    int t = blk >> 7, b = blk & 127;
    const float* src = x + ((size_t)b * T_LEN + t) * 700;
    __bf16* dst = Xb + (size_t)blk * 704;
    for (int c = threadIdx.x; c < 704; c += 256) dst[c] = (c < 700) ? (__bf16)src[c] : (__bf16)0.f;
    return;
  }
  blk -= 12800;
  if (blk == 0) {
    for (int i = threadIdx.x; i < 1024; i += 256) stats[i] = 0.f;
  }
}

// Main GEMM body, BK=64: Z[k=(r,t)][n=(b,o)] = A @ Wr^T. job = t0*NOC + oci.
template <int CINP, int BLK_N, int WROWS, int WCOLS, int CO_SH, int NOC>
__device__ __forceinline__ void gemm_body(char* smem, int job,
    const __bf16* __restrict__ A, const __bf16* __restrict__ Bm,
    __bf16* __restrict__ Z) {
  constexpr int COUTP = 1 << CO_SH;
  constexpr int WM = 128 / WROWS;
  constexpr int WN = BLK_N / WCOLS;
  constexpr int RM = WM / 16;
  constexpr int RN = WN / 16;
  __bf16* sA = (__bf16*)smem;                    // 128*64*2 = 16384 B
  __bf16* sB = (__bf16*)(smem + 16384);          // BLK_N*64*2

  const int tid = threadIdx.x;
  const int w = tid >> 6, lane = tid & 63;
  const int q = lane >> 4, ln = lane & 15;
  const int wrow = w / WCOLS, wcol = w % WCOLS;
  const int srow8 = lane >> 3;
  const int s8 = lane & 7;

  const int t0 = job / NOC;
  const int oc = (job % NOC) * BLK_N;
  const __bf16* Abase = A + (size_t)t0 * 128 * CINP;
  const __bf16* Bbase = Bm + (size_t)oc * CINP;

  v4f acc[RM][RN];
#pragma unroll
  for (int a = 0; a < RM; ++a)
#pragma unroll
    for (int b = 0; b < RN; ++b) acc[a][b] = v4f{0.f, 0.f, 0.f, 0.f};

  for (int ic = 0; ic < CINP; ic += 64) {
    for (int j = w; j < 16; j += 4) {  // A: 128 rows, 8 rows/issue
      int m = j * 8 + srow8;
      int g = s8 ^ (m & 7);
      gl_lds16(Abase + (size_t)m * CINP + ic + g * 8, &sA[j * 512]);
    }
    for (int j = w; j < BLK_N / 8; j += 4) {  // B
      int n = j * 8 + srow8;
      int g = s8 ^ (n & 7);
      gl_lds16(Bbase + (size_t)n * CINP + ic + g * 8, &sB[j * 512]);
    }
    __syncthreads();

#pragma unroll
    for (int s = 0; s < 2; ++s) {
      v8bf af[RM], bfr[RN];
#pragma unroll
      for (int a = 0; a < RM; ++a) {
        int m = wrow * WM + a * 16 + ln;
        af[a] = *(const v8bf*)&sA[m * 64 + ((((s << 2) | q) ^ (m & 7)) * 8)];
      }
#pragma unroll
      for (int b = 0; b < RN; ++b) {
        int n = wcol * WN + b * 16 + ln;
        bfr[b] = *(const v8bf*)&sB[n * 64 + ((((s << 2) | q) ^ (n & 7)) * 8)];
      }
#pragma unroll
      for (int a = 0; a < RM; ++a)
#pragma unroll
        for (int b = 0; b < RN; ++b)
          acc[a][b] = __builtin_amdgcn_mfma_f32_16x16x32_bf16(af[a], bfr[b], acc[a][b], 0, 0, 0);
    }
    __syncthreads();
  }

  // C/D: col=lane&15, row=quad*4+reg (m89-verified)
#pragma unroll
  for (int a = 0; a < RM; ++a) {
#pragma unroll
    for (int b = 0; b < RN; ++b) {
      int n = oc + wcol * WN + b * 16 + ln;
      int r = n >> CO_SH, o = n & (COUTP - 1);
#pragma unroll
      for (int rr = 0; rr < 4; ++rr) {
        int m = t0 * 128 + wrow * WM + a * 16 + q * 4 + rr;
        Z[((size_t)r * M_ROWS + m) * COUTP + o] = (__bf16)acc[a][b][rr];
      }
    }
  }
}

// FIR GEMM body, BK=64, K=448. smem needs 26624 B.
template <int COUTP, bool STATS, bool SOFTMAX>
__device__ __forceinline__ void fir_body(char* smem, int job,
    const __bf16* __restrict__ Af, const __bf16* __restrict__ Z,
    __bf16* __restrict__ Yout, float* __restrict__ stats,
    float* __restrict__ outp, int N) {
  __bf16* sA = (__bf16*)smem;               // 112*64*2 = 14336 B
  uint32* sBu = (uint32*)(smem + 14336);    // 64*35*4  =  8960 B

  const int tid = threadIdx.x;
  const int w = tid >> 6, lane = tid & 63;
  const int q = lane >> 4, ln = lane & 15;
  const int srow8 = lane >> 3, s8 = lane & 7;
  const int kp = tid >> 3;    // 0..31
  const int noct = tid & 7;   // 0..7
  const int nb = job * 64;

  v4f acc[7];
#pragma unroll
  for (int a = 0; a < 7; ++a) acc[a] = v4f{0.f, 0.f, 0.f, 0.f};

  for (int kc = 0; kc < K_FIR; kc += 64) {
    for (int j = w; j < 14; j += 4) {  // stage A (112 x 64)
      int m = j * 8 + srow8;
      int g = s8 ^ (m & 7);
      gl_lds16(Af + (size_t)m * K_FIR + kc + g * 8, &sA[j * 512]);
    }
    // stage B transposed
    const __bf16* zp = Z + (size_t)(kc + kp * 2) * N + nb + noct * 8;
    uint4 r0 = *(const uint4*)zp;
    uint4 r1 = *(const uint4*)(zp + N);
    const ushort_t* p0 = (const ushort_t*)&r0;
    const ushort_t* p1 = (const ushort_t*)&r1;
#pragma unroll
    for (int j = 0; j < 8; ++j) {
      uint32 val = (uint32)p0[j] | ((uint32)p1[j] << 16);
      sBu[(noct * 8 + j) * 35 + kp] = val;
    }
    __syncthreads();

#pragma unroll
    for (int s = 0; s < 2; ++s) {
      v8bf af[7];
#pragma unroll
      for (int a = 0; a < 7; ++a) {
        int m = a * 16 + ln;
        af[a] = *(const v8bf*)&sA[m * 64 + ((((s << 2) | q) ^ (m & 7)) * 8)];
      }
      int base = (w * 16 + ln) * 35 + s * 16 + q * 4;
      uint32 tmp[4] = {sBu[base], sBu[base + 1], sBu[base + 2], sBu[base + 3]};
      v8bf bfr = *(const v8bf*)tmp;
#pragma unroll
      for (int a = 0; a < 7; ++a)
        acc[a] = __builtin_amdgcn_mfma_f32_16x16x32_bf16(af[a], bfr, acc[a], 0, 0, 0);
    }
    __syncthreads();
  }

  int ng = nb + w * 16 + ln;
  if (!SOFTMAX) {
    float s = 0.f, ss = 0.f;
#pragma unroll
    for (int a = 0; a < 7; ++a) {
#pragma unroll
      for (int rr = 0; rr < 4; ++rr) {
        int t = a * 16 + q * 4 + rr;
        float v = acc[a][rr];
        if (t < 100) {
          Yout[(size_t)t * N + ng] = (__bf16)v;
          s += v; ss += v * v;
        }
      }
    }
    if (STATS) {
      s += __shfl_xor(s, 16); ss += __shfl_xor(ss, 16);
      s += __shfl_xor(s, 32); ss += __shfl_xor(ss, 32);
      if (q == 0) {
        int o = ng & (COUTP - 1);
        atomicAdd(&stats[o], s);
        atomicAdd(&stats[COUTP + o], ss);
      }
    }
  } else {
    // this block holds all t and all o for 2 batch entries
    float* smx = (float*)smem;               // [100][65] = 26000 B
    float* lacc = (float*)(smem + 26000);    // 40 floats
    int col = w * 16 + ln;
#pragma unroll
    for (int a = 0; a < 7; ++a) {
#pragma unroll
      for (int rr = 0; rr < 4; ++rr) {
        int t = a * 16 + q * 4 + rr;
        if (t < 100) smx[t * 65 + col] = acc[a][rr];
      }
    }
    if (tid < 64) lacc[tid & 63] = 0.f;
    __syncthreads();
    if (tid < 200) {
      int bl = tid / 100, t = tid - bl * 100;
      const float* rr = &smx[t * 65 + bl * 32];
      float v[20], m = -1e30f;
#pragma unroll
      for (int o = 0; o < 20; ++o) { v[o] = rr[o]; m = fmaxf(m, v[o]); }
      float sum = 0.f;
#pragma unroll
      for (int o = 0; o < 20; ++o) { v[o] = expf(v[o] - m); sum += v[o]; }
      float inv = 1.f / sum;
#pragma unroll
      for (int o = 0; o < 20; ++o) atomicAdd(&lacc[bl * 20 + o], v[o] * inv);
    }
    __syncthreads();
    if (tid < 40) {
      int bl = tid / 20, o = tid - bl * 20;
      int b = (nb >> 5) + bl;
      outp[b * 20 + o] = lacc[bl * 20 + o];
    }
    __syncthreads();  // protect smem reuse
  }
}

// BN+ReLU on one uint4 (8 channels), in-place. idx < BN_ITEMS (409600).
__device__ __forceinline__ void bn_item(int idx, __bf16* __restrict__ h,
    const float* __restrict__ stats, const float* __restrict__ gamma,
    const float* __restrict__ beta) {
  int co = (idx & 31) * 8;
  size_t row = (size_t)(idx >> 5);
  __bf16* p = h + row * 256 + co;
  uint4 raw = *(const uint4*)p;
  const ushort_t* pr = (const ushort_t*)&raw;
  uint4 outv;
  ushort_t* po = (ushort_t*)&outv;
#pragma unroll
  for (int j = 0; j < 8; ++j) {
    int c = co + j;
    float mean = stats[c] * (1.f / 12800.f);
    float var = stats[256 + c] * (1.f / 12800.f) - mean * mean;
    float inv = rsqrtf(var + 1e-5f) * gamma[c];
    uint32 u = (uint32)pr[j] << 16;
    float xv; __builtin_memcpy(&xv, &u, 4);
    float v = (xv - mean) * inv + beta[c];
    v = fmaxf(v, 0.f);
    __bf16 bv = (__bf16)v;
    po[j] = *(const ushort_t*)&bv;
  }
  *(uint4*)p = outv;
}

// ---------------------------------------------------------------------------
// Cooperative mega-kernel: all 9 phases, 8 grid syncs, one dispatch.
// ---------------------------------------------------------------------------
__global__ __launch_bounds__(256, 2)
void mega(const float* x, const float* W1, const float* P1, const float* W2,
          const float* P2, const float* W3, const float* P3,
          const float* g1, const float* b1, const float* g2, const float* b2,
          __bf16* Xb, __bf16* Zb, __bf16* Yb, __bf16* Wr1, __bf16* Wr2,
          __bf16* Wr3, __bf16* Af, float* stats1, float* stats2, float* out) {
  cg::grid_group grid = cg::this_grid();
  __shared__ __align__(16) char smem[49152];
  const int NB = gridDim.x;
  const int bid = blockIdx.x;

  for (int vb = bid; vb < SETUP_JOBS; vb += NB)
    setup_body(vb, x, W1, P1, W2, P2, W3, P3, Xb, Wr1, Wr2, Wr3, Af, stats1);
  __threadfence(); grid.sync();

  for (int j = bid; j < 400; j += NB)                       // gemm1
    gemm_body<704, 256, 2, 2, 8, 4>(smem, j, Xb, Wr1, Zb);
  __threadfence(); grid.sync();

  for (int j = bid; j < 512; j += NB)                       // fir1 + stats
    fir_body<256, true, false>(smem, j, Af, Zb, Yb, stats1, nullptr, 32768);
  __threadfence(); grid.sync();

  for (int idx = bid * 256 + threadIdx.x; idx < BN_ITEMS; idx += NB * 256)
    bn_item(idx, Yb, stats1, g1, b1);                       // bn1
  __threadfence(); grid.sync();

  for (int j = bid; j < 400; j += NB)                       // gemm2
    gemm_body<256, 256, 2, 2, 8, 4>(smem, j, Yb, Wr2, Zb);
  __threadfence(); grid.sync();

  for (int j = bid; j < 512; j += NB)                       // fir2 + stats
    fir_body<256, true, false>(smem, j, Af, Zb, Yb, stats2, nullptr, 32768);
  __threadfence(); grid.sync();

  for (int idx = bid * 256 + threadIdx.x; idx < BN_ITEMS; idx += NB * 256)
    bn_item(idx, Yb, stats2, g2, b2);                       // bn2
  __threadfence(); grid.sync();

  for (int j = bid; j < 200; j += NB)                       // gemm3
    gemm_body<256, 64, 2, 2, 5, 2>(smem, j, Yb, Wr3, Zb);
  __threadfence(); grid.sync();

  for (int j = bid; j < 64; j += NB)                        // fir3 + softmax/sum
    fir_body<32, false, true>(smem, j, Af, Zb, nullptr, nullptr, out, 4096);
}

// ---------------------------------------------------------------------------
// Fallback wrappers (R7 multi-dispatch path)
// ---------------------------------------------------------------------------
__global__ void setup_all(const float* x, const float* W1, const float* P1,
                          const float* W2, const float* P2, const float* W3,
                          const float* P3, __bf16* Xb, __bf16* Wr1, __bf16* Wr2,
                          __bf16* Wr3, __bf16* Af, float* stats) {
  setup_body(blockIdx.x, x, W1, P1, W2, P2, W3, P3, Xb, Wr1, Wr2, Wr3, Af, stats);
}

template <int CINP, int BLK_N, int WROWS, int WCOLS, int CO_SH, int NOC>
__global__ __launch_bounds__(256, 2)
void gemm_k(const __bf16* A, const __bf16* Bm, __bf16* Z) {
  __shared__ __align__(16) char smem[16384 + BLK_N * 128];
  gemm_body<CINP, BLK_N, WROWS, WCOLS, CO_SH, NOC>(smem, blockIdx.x, A, Bm, Z);
}

template <int COUTP, bool STATS, bool SOFTMAX>
__global__ __launch_bounds__(256, 2)
void fir_k(const __bf16* Af, const __bf16* Z, __bf16* Yout, float* stats,
           float* outp, int N) {
  __shared__ __align__(16) char smem[26624];
  fir_body<COUTP, STATS, SOFTMAX>(smem, blockIdx.x, Af, Z, Yout, stats, outp, N);
}

__global__ __launch_bounds__(256)
void bn_k(__bf16* h, const float* stats, const float* gamma, const float* beta) {
  bn_item(blockIdx.x * 256 + threadIdx.x, h, stats, gamma, beta);
}

// ---------------------------------------------------------------------------

extern "C" void kernel_launch(void* const* d_in, const int* in_sizes, int n_in,
                              void* d_out, int out_size, void* d_ws, size_t ws_size,
                              hipStream_t stream) {
  const float* x  = (const float*)d_in[0];
  const float* W1 = (const float*)d_in[1];
  const float* P1 = (const float*)d_in[2];
  const float* W2 = (const float*)d_in[3];
  const float* P2 = (const float*)d_in[4];
  const float* W3 = (const float*)d_in[5];
  const float* P3 = (const float*)d_in[6];
  const float* g1 = (const float*)d_in[7];
  const float* b1 = (const float*)d_in[8];
  const float* g2 = (const float*)d_in[9];
  const float* b2 = (const float*)d_in[10];
  float* out = (float*)d_out;

  constexpr size_t XB_B  = (size_t)M_ROWS * 704 * 2;
  constexpr size_t Z_B   = (size_t)K_FIR * 32768 * 2;
  constexpr size_t Y12_B = (size_t)M_ROWS * 256 * 2;
  constexpr size_t W1_B  = (size_t)R_RANK * 256 * 704 * 2;
  constexpr size_t W2_B  = (size_t)R_RANK * 256 * 256 * 2;
  constexpr size_t W3_B  = (size_t)R_RANK * 32 * 256 * 2;
  constexpr size_t AF_B  = (size_t)112 * K_FIR * 2;
  constexpr size_t ST_B  = 4096;
  constexpr size_t TOTAL = XB_B + Z_B + Y12_B + W1_B + W2_B + W3_B + AF_B + ST_B;
  if (ws_size < TOTAL) return;

  char* ws = (char*)d_ws;
  size_t off = 0;
  __bf16* Xb   = (__bf16*)(ws + off); off += XB_B;
  __bf16* Zb   = (__bf16*)(ws + off); off += Z_B;
  __bf16* Yb   = (__bf16*)(ws + off); off += Y12_B;
  __bf16* Wr1  = (__bf16*)(ws + off); off += W1_B;
  __bf16* Wr2  = (__bf16*)(ws + off); off += W2_B;
  __bf16* Wr3  = (__bf16*)(ws + off); off += W3_B;
  __bf16* Afir = (__bf16*)(ws + off); off += AF_B;
  float*  stats1 = (float*)(ws + off);
  float*  stats2 = stats1 + 512;

  int dev = 0;
  hipGetDevice(&dev);
  int coop = 0;
  hipDeviceGetAttribute(&coop, hipDeviceAttributeCooperativeLaunch, dev);

  bool launched = false;
  if (coop) {
    void* args[] = {(void*)&x, (void*)&W1, (void*)&P1, (void*)&W2, (void*)&P2,
                    (void*)&W3, (void*)&P3, (void*)&g1, (void*)&b1, (void*)&g2,
                    (void*)&b2, (void*)&Xb, (void*)&Zb, (void*)&Yb, (void*)&Wr1,
                    (void*)&Wr2, (void*)&Wr3, (void*)&Afir, (void*)&stats1,
                    (void*)&stats2, (void*)&out};
    hipError_t e = hipLaunchCooperativeKernel((const void*)mega, dim3(512),
                                              dim3(256), args, 0, stream);
    launched = (e == hipSuccess);
  }

  if (!launched) {
    // R7 multi-dispatch fallback (identical math)
    setup_all<<<dim3(SETUP_JOBS), 256, 0, stream>>>(x, W1, P1, W2, P2, W3, P3,
                                                    Xb, Wr1, Wr2, Wr3, Afir, stats1);
    gemm_k<704, 256, 2, 2, 8, 4><<<dim3(400), 256, 0, stream>>>(Xb, Wr1, Zb);
    fir_k<256, true, false><<<dim3(512), 256, 0, stream>>>(Afir, Zb, Yb, stats1, nullptr, 32768);
    bn_k<<<dim3(1600), 256, 0, stream>>>(Yb, stats1, g1, b1);
    gemm_k<256, 256, 2, 2, 8, 4><<<dim3(400), 256, 0, stream>>>(Yb, Wr2, Zb);
    fir_k<256, true, false><<<dim3(512), 256, 0, stream>>>(Afir, Zb, Yb, stats2, nullptr, 32768);
    bn_k<<<dim3(1600), 256, 0, stream>>>(Yb, stats2, g2, b2);
    gemm_k<256, 64, 2, 2, 5, 2><<<dim3(200), 256, 0, stream>>>(Yb, Wr3, Zb);
    fir_k<32, false, true><<<dim3(64), 256, 0, stream>>>(Afir, Zb, nullptr, nullptr, out, 4096);
  }
}

// Round 10
// 210.876 us; speedup vs baseline: 5.4682x; 5.4682x over previous
//
#include <hip/hip_runtime.h>
#include <stdint.h>

// ---------------------------------------------------------------------------
// d128snn_delays, round 10: rank-4 Chebyshev DCLS + FIR-as-GEMM (BK=64),
// 9-dispatch structure (R7). Cooperative mega-kernel abandoned: R9 measured
// grid.sync() at ~110us each on gfx950 (8 syncs -> +900us). New in R10:
//   - XCD-aware block swizzle in gemm: the NOC oc-blocks sharing one A-tile
//     map to the same XCD (blockIdx%8) -> A re-reads hit per-XCD L2.
//   - vectorized fill_xb (float4 -> bf16x4, 2 rows/block).
// ---------------------------------------------------------------------------

#define T_LEN 100
#define B_SZ  128
#define M_ROWS 12800
#define R_RANK 4
#define K_FIR 448
#define BN_ITEMS 409600   // 12800 rows * (256 ch / 8 per uint4)

typedef __bf16 v8bf __attribute__((ext_vector_type(8)));
typedef float  v4f  __attribute__((ext_vector_type(4)));
typedef unsigned int uint32;
typedef unsigned short ushort_t;

// PHI[tau][r] = exp(-u^2/2) * T_r(u), u = (tau-12)/12  (Chebyshev basis)
struct PhiT { float v[25][R_RANK]; };
constexpr double cexp_(double x) {
  double s = 1.0, t = 1.0;
  for (int n = 1; n < 30; ++n) { t = t * x / n; s += t; }
  return s;
}
constexpr PhiT make_phi() {
  PhiT P{};
  for (int tau = 0; tau < 25; ++tau) {
    double u = (tau - 12) / 12.0;
    double g = cexp_(-0.5 * u * u);
    double T0 = 1.0, T1 = u;
    P.v[tau][0] = (float)(g * T0);
    P.v[tau][1] = (float)(g * T1);
    for (int r = 2; r < R_RANK; ++r) {
      double T2 = 2.0 * u * T1 - T0;
      P.v[tau][r] = (float)(g * T2);
      T0 = T1; T1 = T2;
    }
  }
  return P;
}
constexpr PhiT PHI = make_phi();

__device__ __forceinline__ void gl_lds16(const void* g, void* l) {
  __builtin_amdgcn_global_load_lds(
      (const __attribute__((address_space(1))) char*)g,
      (__attribute__((address_space(3))) char*)l, 16, 0, 0);
}

// ---------------------------------------------------------------------------
// Setup: 3x build_wr (Chebyshev/Bessel) + build_afir + fill_xb(x4 vec) + stats0
// ---------------------------------------------------------------------------
__device__ __forceinline__ void build_wr_body(
    const float* __restrict__ W, const float* __restrict__ P,
    __bf16* __restrict__ Wr, int CIN, int CINP, int COUT, int COUTP, int o) {
  for (int i = threadIdx.x; i < CINP; i += blockDim.x) {
    bool valid = (o < COUT) && (i < CIN);
    float w = valid ? W[(size_t)o * CIN + i] : 0.f;
    float p = valid ? P[(size_t)o * CIN + i] : 0.f;
    float S = 0.f;
#pragma unroll
    for (int l = 0; l < 25; ++l) {
      float d = ((float)(l - 12) - p) * (1.f / 12.f);
      S += expf(-0.5f * d * d);
    }
    float v = p * (1.f / 12.f);
    float g = w * expf(-0.5f * v * v) / (S + 1e-7f);
    float h = 0.5f * v, hh = h * h;
    float pw = 1.f;  // h^r / r!
#pragma unroll
    for (int r = 0; r < R_RANK; ++r) {
      float term = pw, sum = pw;
#pragma unroll
      for (int m = 1; m <= 6; ++m) {
        term *= hh / (float)(m * (m + r));
        sum += term;
      }
      float c = g * ((r == 0) ? 1.f : 2.f) * sum;
      Wr[((size_t)r * COUTP + o) * CINP + i] = (__bf16)c;
      pw *= h / (float)(r + 1);
    }
  }
}

#define SETUP_JOBS 7141   // 256 + 256 + 32 + 196 + 6400 + 1
__global__ void setup_all(const float* __restrict__ x,
                          const float* __restrict__ W1, const float* __restrict__ P1,
                          const float* __restrict__ W2, const float* __restrict__ P2,
                          const float* __restrict__ W3, const float* __restrict__ P3,
                          __bf16* __restrict__ Xb, __bf16* __restrict__ Wr1,
                          __bf16* __restrict__ Wr2, __bf16* __restrict__ Wr3,
                          __bf16* __restrict__ Af, float* __restrict__ stats) {
  int blk = blockIdx.x;
  if (blk < 256) { build_wr_body(W1, P1, Wr1, 700, 704, 256, 256, blk); return; }
  blk -= 256;
  if (blk < 256) { build_wr_body(W2, P2, Wr2, 256, 256, 256, 256, blk); return; }
  blk -= 256;
  if (blk < 32) { build_wr_body(W3, P3, Wr3, 256, 256, 20, 32, blk); return; }
  blk -= 32;
  if (blk < 196) {  // Afir (112 x 448): [t][r*100+s] = PHI[s-t+24][r], else 0
    int idx = blk * 256 + threadIdx.x;
    if (idx < 112 * 448) {
      int t = idx / 448, k = idx - t * 448;
      float v = 0.f;
      if (t < 100 && k < 400) {
        int r = k / 100, s = k - r * 100;
        int tau = s - t + 24;
        if (tau >= 0 && tau < 25) v = PHI.v[tau][r];
      }
      Af[idx] = (__bf16)v;
    }
    return;
  }
  blk -= 196;
  if (blk < 6400) {  // x (B,T,700) f32 -> Xb (T,B,704) bf16, 2 rows/block, x4 vec
    int tid = threadIdx.x;
    if (tid < 176) {
      int c4 = tid * 4;
#pragma unroll
      for (int rr = 0; rr < 2; ++rr) {
        int tb = blk * 2 + rr;
        int t = tb >> 7, b = tb & 127;
        const float* src = x + ((size_t)b * T_LEN + t) * 700;
        __bf16* dst = Xb + (size_t)tb * 704;
        __bf16 o4[4];
        if (c4 < 700) {
          float4 v = *(const float4*)(src + c4);
          o4[0] = (__bf16)v.x; o4[1] = (__bf16)v.y;
          o4[2] = (__bf16)v.z; o4[3] = (__bf16)v.w;
        } else {
          o4[0] = o4[1] = o4[2] = o4[3] = (__bf16)0.f;
        }
        *(uint2*)(dst + c4) = *(const uint2*)o4;
      }
    }
    return;
  }
  blk -= 6400;
  if (blk == 0) {
    for (int i = threadIdx.x; i < 1024; i += 256) stats[i] = 0.f;
  }
}

// ---------------------------------------------------------------------------
// Main GEMM body, BK=64: Z[k=(r,t)][n=(b,o)] = A @ Wr^T. job = t0*NOC + oci.
// ---------------------------------------------------------------------------
template <int CINP, int BLK_N, int WROWS, int WCOLS, int CO_SH, int NOC>
__device__ __forceinline__ void gemm_body(char* smem, int job,
    const __bf16* __restrict__ A, const __bf16* __restrict__ Bm,
    __bf16* __restrict__ Z) {
  constexpr int COUTP = 1 << CO_SH;
  constexpr int WM = 128 / WROWS;
  constexpr int WN = BLK_N / WCOLS;
  constexpr int RM = WM / 16;
  constexpr int RN = WN / 16;
  __bf16* sA = (__bf16*)smem;                    // 128*64*2 = 16384 B
  __bf16* sB = (__bf16*)(smem + 16384);          // BLK_N*64*2

  const int tid = threadIdx.x;
  const int w = tid >> 6, lane = tid & 63;
  const int q = lane >> 4, ln = lane & 15;
  const int wrow = w / WCOLS, wcol = w % WCOLS;
  const int srow8 = lane >> 3;
  const int s8 = lane & 7;

  const int t0 = job / NOC;
  const int oc = (job % NOC) * BLK_N;
  const __bf16* Abase = A + (size_t)t0 * 128 * CINP;
  const __bf16* Bbase = Bm + (size_t)oc * CINP;

  v4f acc[RM][RN];
#pragma unroll
  for (int a = 0; a < RM; ++a)
#pragma unroll
    for (int b = 0; b < RN; ++b) acc[a][b] = v4f{0.f, 0.f, 0.f, 0.f};

  for (int ic = 0; ic < CINP; ic += 64) {
    for (int j = w; j < 16; j += 4) {  // A: 128 rows, 8 rows/issue
      int m = j * 8 + srow8;
      int g = s8 ^ (m & 7);
      gl_lds16(Abase + (size_t)m * CINP + ic + g * 8, &sA[j * 512]);
    }
    for (int j = w; j < BLK_N / 8; j += 4) {  // B
      int n = j * 8 + srow8;
      int g = s8 ^ (n & 7);
      gl_lds16(Bbase + (size_t)n * CINP + ic + g * 8, &sB[j * 512]);
    }
    __syncthreads();

#pragma unroll
    for (int s = 0; s < 2; ++s) {
      v8bf af[RM], bfr[RN];
#pragma unroll
      for (int a = 0; a < RM; ++a) {
        int m = wrow * WM + a * 16 + ln;
        af[a] = *(const v8bf*)&sA[m * 64 + ((((s << 2) | q) ^ (m & 7)) * 8)];
      }
#pragma unroll
      for (int b = 0; b < RN; ++b) {
        int n = wcol * WN + b * 16 + ln;
        bfr[b] = *(const v8bf*)&sB[n * 64 + ((((s << 2) | q) ^ (n & 7)) * 8)];
      }
#pragma unroll
      for (int a = 0; a < RM; ++a)
#pragma unroll
        for (int b = 0; b < RN; ++b)
          acc[a][b] = __builtin_amdgcn_mfma_f32_16x16x32_bf16(af[a], bfr[b], acc[a][b], 0, 0, 0);
    }
    __syncthreads();
  }

  // C/D: col=lane&15, row=quad*4+reg (m89-verified)
#pragma unroll
  for (int a = 0; a < RM; ++a) {
#pragma unroll
    for (int b = 0; b < RN; ++b) {
      int n = oc + wcol * WN + b * 16 + ln;
      int r = n >> CO_SH, o = n & (COUTP - 1);
#pragma unroll
      for (int rr = 0; rr < 4; ++rr) {
        int m = t0 * 128 + wrow * WM + a * 16 + q * 4 + rr;
        Z[((size_t)r * M_ROWS + m) * COUTP + o] = (__bf16)acc[a][b][rr];
      }
    }
  }
}

// GEMM wrapper with XCD-aware swizzle: the NOC oc-blocks of one t0 map to
// blockIdx values congruent mod 8 -> same XCD -> shared A-tile hits L2.
// Grid = 13 * 8 * NOC (t0 groups padded 100 -> 104).
template <int CINP, int BLK_N, int WROWS, int WCOLS, int CO_SH, int NOC>
__global__ __launch_bounds__(256, 2)
void gemm_k(const __bf16* A, const __bf16* Bm, __bf16* Z) {
  __shared__ __align__(16) char smem[16384 + BLK_N * 128];
  int b = blockIdx.x;
  int q = b / (8 * NOC);
  int rem = b - q * 8 * NOC;
  int r = rem & 7;
  int i = rem >> 3;
  int t0 = q * 8 + r;
  if (t0 >= 100) return;
  gemm_body<CINP, BLK_N, WROWS, WCOLS, CO_SH, NOC>(smem, t0 * NOC + i, A, Bm, Z);
}

// ---------------------------------------------------------------------------
// FIR GEMM, BK=64, K=448: Y(112 x 64-slice) = Afir(112x448) @ Z(448xN).
// ---------------------------------------------------------------------------
template <int COUTP, bool STATS, bool SOFTMAX>
__global__ __launch_bounds__(256, 2)
void fir_k(const __bf16* __restrict__ Af, const __bf16* __restrict__ Z,
           __bf16* __restrict__ Yout, float* __restrict__ stats,
           float* __restrict__ outp, int N) {
  __shared__ __align__(16) unsigned char smem[26624];
  __bf16* sA = (__bf16*)smem;               // 112*64*2 = 14336 B
  uint32* sBu = (uint32*)(smem + 14336);    // 64*35*4  =  8960 B

  const int tid = threadIdx.x;
  const int w = tid >> 6, lane = tid & 63;
  const int q = lane >> 4, ln = lane & 15;
  const int srow8 = lane >> 3, s8 = lane & 7;
  const int kp = tid >> 3;    // 0..31
  const int noct = tid & 7;   // 0..7
  const int nb = blockIdx.x * 64;

  v4f acc[7];
#pragma unroll
  for (int a = 0; a < 7; ++a) acc[a] = v4f{0.f, 0.f, 0.f, 0.f};

  for (int kc = 0; kc < K_FIR; kc += 64) {
    for (int j = w; j < 14; j += 4) {  // stage A (112 x 64)
      int m = j * 8 + srow8;
      int g = s8 ^ (m & 7);
      gl_lds16(Af + (size_t)m * K_FIR + kc + g * 8, &sA[j * 512]);
    }
    // stage B transposed
    const __bf16* zp = Z + (size_t)(kc + kp * 2) * N + nb + noct * 8;
    uint4 r0 = *(const uint4*)zp;
    uint4 r1 = *(const uint4*)(zp + N);
    const ushort_t* p0 = (const ushort_t*)&r0;
    const ushort_t* p1 = (const ushort_t*)&r1;
#pragma unroll
    for (int j = 0; j < 8; ++j) {
      uint32 val = (uint32)p0[j] | ((uint32)p1[j] << 16);
      sBu[(noct * 8 + j) * 35 + kp] = val;
    }
    __syncthreads();

#pragma unroll
    for (int s = 0; s < 2; ++s) {
      v8bf af[7];
#pragma unroll
      for (int a = 0; a < 7; ++a) {
        int m = a * 16 + ln;
        af[a] = *(const v8bf*)&sA[m * 64 + ((((s << 2) | q) ^ (m & 7)) * 8)];
      }
      int base = (w * 16 + ln) * 35 + s * 16 + q * 4;
      uint32 tmp[4] = {sBu[base], sBu[base + 1], sBu[base + 2], sBu[base + 3]};
      v8bf bfr = *(const v8bf*)tmp;
#pragma unroll
      for (int a = 0; a < 7; ++a)
        acc[a] = __builtin_amdgcn_mfma_f32_16x16x32_bf16(af[a], bfr, acc[a], 0, 0, 0);
    }
    __syncthreads();
  }

  int ng = nb + w * 16 + ln;
  if (!SOFTMAX) {
    float s = 0.f, ss = 0.f;
#pragma unroll
    for (int a = 0; a < 7; ++a) {
#pragma unroll
      for (int rr = 0; rr < 4; ++rr) {
        int t = a * 16 + q * 4 + rr;
        float v = acc[a][rr];
        if (t < 100) {
          Yout[(size_t)t * N + ng] = (__bf16)v;
          s += v; ss += v * v;
        }
      }
    }
    if (STATS) {
      s += __shfl_xor(s, 16); ss += __shfl_xor(ss, 16);
      s += __shfl_xor(s, 32); ss += __shfl_xor(ss, 32);
      if (q == 0) {
        int o = ng & (COUTP - 1);
        atomicAdd(&stats[o], s);
        atomicAdd(&stats[COUTP + o], ss);
      }
    }
  } else {
    // this block holds all t and all o for 2 batch entries
    float* smx = (float*)smem;               // [100][65] = 26000 B
    float* lacc = (float*)(smem + 26000);    // 40 floats
    int col = w * 16 + ln;
#pragma unroll
    for (int a = 0; a < 7; ++a) {
#pragma unroll
      for (int rr = 0; rr < 4; ++rr) {
        int t = a * 16 + q * 4 + rr;
        if (t < 100) smx[t * 65 + col] = acc[a][rr];
      }
    }
    if (tid < 64) lacc[tid & 63] = 0.f;
    __syncthreads();
    if (tid < 200) {
      int bl = tid / 100, t = tid - bl * 100;
      const float* rr = &smx[t * 65 + bl * 32];
      float v[20], m = -1e30f;
#pragma unroll
      for (int o = 0; o < 20; ++o) { v[o] = rr[o]; m = fmaxf(m, v[o]); }
      float sum = 0.f;
#pragma unroll
      for (int o = 0; o < 20; ++o) { v[o] = expf(v[o] - m); sum += v[o]; }
      float inv = 1.f / sum;
#pragma unroll
      for (int o = 0; o < 20; ++o) atomicAdd(&lacc[bl * 20 + o], v[o] * inv);
    }
    __syncthreads();
    if (tid < 40) {
      int bl = tid / 20, o = tid - bl * 20;
      int b = (nb >> 5) + bl;
      outp[b * 20 + o] = lacc[bl * 20 + o];
    }
  }
}

// BN+ReLU, bf16x8 vectorized, in-place. grid 1600 x 256 covers 409600 items.
__global__ __launch_bounds__(256)
void bn_k(__bf16* __restrict__ h, const float* __restrict__ stats,
          const float* __restrict__ gamma, const float* __restrict__ beta) {
  int idx = blockIdx.x * 256 + threadIdx.x;
  int co = (idx & 31) * 8;
  size_t row = (size_t)(idx >> 5);
  __bf16* p = h + row * 256 + co;
  uint4 raw = *(const uint4*)p;
  const ushort_t* pr = (const ushort_t*)&raw;
  uint4 outv;
  ushort_t* po = (ushort_t*)&outv;
#pragma unroll
  for (int j = 0; j < 8; ++j) {
    int c = co + j;
    float mean = stats[c] * (1.f / 12800.f);
    float var = stats[256 + c] * (1.f / 12800.f) - mean * mean;
    float inv = rsqrtf(var + 1e-5f) * gamma[c];
    uint32 u = (uint32)pr[j] << 16;
    float xv; __builtin_memcpy(&xv, &u, 4);
    float v = (xv - mean) * inv + beta[c];
    v = fmaxf(v, 0.f);
    __bf16 bv = (__bf16)v;
    po[j] = *(const ushort_t*)&bv;
  }
  *(uint4*)p = outv;
}

// ---------------------------------------------------------------------------

extern "C" void kernel_launch(void* const* d_in, const int* in_sizes, int n_in,
                              void* d_out, int out_size, void* d_ws, size_t ws_size,
                              hipStream_t stream) {
  const float* x  = (const float*)d_in[0];
  const float* W1 = (const float*)d_in[1];
  const float* P1 = (const float*)d_in[2];
  const float* W2 = (const float*)d_in[3];
  const float* P2 = (const float*)d_in[4];
  const float* W3 = (const float*)d_in[5];
  const float* P3 = (const float*)d_in[6];
  const float* g1 = (const float*)d_in[7];
  const float* b1 = (const float*)d_in[8];
  const float* g2 = (const float*)d_in[9];
  const float* b2 = (const float*)d_in[10];
  float* out = (float*)d_out;

  constexpr size_t XB_B  = (size_t)M_ROWS * 704 * 2;
  constexpr size_t Z_B   = (size_t)K_FIR * 32768 * 2;
  constexpr size_t Y12_B = (size_t)M_ROWS * 256 * 2;
  constexpr size_t W1_B  = (size_t)R_RANK * 256 * 704 * 2;
  constexpr size_t W2_B  = (size_t)R_RANK * 256 * 256 * 2;
  constexpr size_t W3_B  = (size_t)R_RANK * 32 * 256 * 2;
  constexpr size_t AF_B  = (size_t)112 * K_FIR * 2;
  constexpr size_t ST_B  = 4096;
  constexpr size_t TOTAL = XB_B + Z_B + Y12_B + W1_B + W2_B + W3_B + AF_B + ST_B;
  if (ws_size < TOTAL) return;

  char* ws = (char*)d_ws;
  size_t off = 0;
  __bf16* Xb   = (__bf16*)(ws + off); off += XB_B;
  __bf16* Zb   = (__bf16*)(ws + off); off += Z_B;
  __bf16* Yb   = (__bf16*)(ws + off); off += Y12_B;
  __bf16* Wr1  = (__bf16*)(ws + off); off += W1_B;
  __bf16* Wr2  = (__bf16*)(ws + off); off += W2_B;
  __bf16* Wr3  = (__bf16*)(ws + off); off += W3_B;
  __bf16* Afir = (__bf16*)(ws + off); off += AF_B;
  float*  stats1 = (float*)(ws + off);
  float*  stats2 = stats1 + 512;

  setup_all<<<dim3(SETUP_JOBS), 256, 0, stream>>>(x, W1, P1, W2, P2, W3, P3,
                                                  Xb, Wr1, Wr2, Wr3, Afir, stats1);

  // layer 1: GEMM (12800 x 1024 x 704), BLK_N=256, XCD-swizzled grid 13*8*4
  gemm_k<704, 256, 2, 2, 8, 4><<<dim3(416), 256, 0, stream>>>(Xb, Wr1, Zb);
  fir_k<256, true, false><<<dim3(512), 256, 0, stream>>>(Afir, Zb, Yb, stats1, nullptr, 32768);
  bn_k<<<dim3(1600), 256, 0, stream>>>(Yb, stats1, g1, b1);

  // layer 2: GEMM (12800 x 1024 x 256)
  gemm_k<256, 256, 2, 2, 8, 4><<<dim3(416), 256, 0, stream>>>(Yb, Wr2, Zb);
  fir_k<256, true, false><<<dim3(512), 256, 0, stream>>>(Afir, Zb, Yb, stats2, nullptr, 32768);
  bn_k<<<dim3(1600), 256, 0, stream>>>(Yb, stats2, g2, b2);

  // layer 3: GEMM (12800 x 128 x 256), grid 13*8*2
  gemm_k<256, 64, 2, 2, 5, 2><<<dim3(208), 256, 0, stream>>>(Yb, Wr3, Zb);
  fir_k<32, false, true><<<dim3(64), 256, 0, stream>>>(Afir, Zb, nullptr, nullptr, out, 4096);
}

// Round 11
// 200.218 us; speedup vs baseline: 5.7593x; 1.0532x over previous
//
#include <hip/hip_runtime.h>
#include <stdint.h>

// ---------------------------------------------------------------------------
// d128snn_delays, round 11 = exact R7 revert (measured best: 200.9 us).
// Rank-4 Chebyshev DCLS + FIR-as-GEMM (BK=64), 9-dispatch structure.
// Measured-dead-end ledger:
//   - inline BN in GEMM staging (R6): +VALU in K-loop critical path, net -.
//   - cooperative mega-kernel (R9): grid.sync() ~110us each on gfx950 -> 5x.
//   - XCD-aware swizzle (R10): serializes A-fill through one XCD's L2; L3
//     already dedupes at this working-set size. -10us.
// Remaining budget: ~42us harness ws-poison fill + ~87us kernels + ~45us
// dispatch boundaries (sequential chain) + restore. Structural floor.
// ---------------------------------------------------------------------------

#define T_LEN 100
#define B_SZ  128
#define M_ROWS 12800
#define R_RANK 4
#define K_FIR 448

typedef __bf16 v8bf __attribute__((ext_vector_type(8)));
typedef float  v4f  __attribute__((ext_vector_type(4)));
typedef unsigned int uint32;
typedef unsigned short ushort_t;

// PHI[tau][r] = exp(-u^2/2) * T_r(u), u = (tau-12)/12  (Chebyshev basis)
struct PhiT { float v[25][R_RANK]; };
constexpr double cexp_(double x) {
  double s = 1.0, t = 1.0;
  for (int n = 1; n < 30; ++n) { t = t * x / n; s += t; }
  return s;
}
constexpr PhiT make_phi() {
  PhiT P{};
  for (int tau = 0; tau < 25; ++tau) {
    double u = (tau - 12) / 12.0;
    double g = cexp_(-0.5 * u * u);
    double T0 = 1.0, T1 = u;
    P.v[tau][0] = (float)(g * T0);
    P.v[tau][1] = (float)(g * T1);
    for (int r = 2; r < R_RANK; ++r) {
      double T2 = 2.0 * u * T1 - T0;
      P.v[tau][r] = (float)(g * T2);
      T0 = T1; T1 = T2;
    }
  }
  return P;
}
constexpr PhiT PHI = make_phi();

__device__ __forceinline__ void gl_lds16(const void* g, void* l) {
  __builtin_amdgcn_global_load_lds(
      (const __attribute__((address_space(1))) char*)g,
      (__attribute__((address_space(3))) char*)l, 16, 0, 0);
}

// ---------------------------------------------------------------------------
// Fused setup: 3x build_wr (Chebyshev/Bessel coeffs) + build_afir + fill_xb
// + stats zero.
// ---------------------------------------------------------------------------
__device__ __forceinline__ void build_wr_body(
    const float* __restrict__ W, const float* __restrict__ P,
    __bf16* __restrict__ Wr, int CIN, int CINP, int COUT, int COUTP, int o) {
  for (int i = threadIdx.x; i < CINP; i += blockDim.x) {
    bool valid = (o < COUT) && (i < CIN);
    float w = valid ? W[(size_t)o * CIN + i] : 0.f;
    float p = valid ? P[(size_t)o * CIN + i] : 0.f;
    float S = 0.f;
#pragma unroll
    for (int l = 0; l < 25; ++l) {
      float d = ((float)(l - 12) - p) * (1.f / 12.f);
      S += expf(-0.5f * d * d);
    }
    float v = p * (1.f / 12.f);
    float g = w * expf(-0.5f * v * v) / (S + 1e-7f);
    // modified Bessel I_r(v), r = 0..3, 7-term series (|v|<=1)
    float h = 0.5f * v, hh = h * h;
    float pw = 1.f;  // h^r / r!
#pragma unroll
    for (int r = 0; r < R_RANK; ++r) {
      float term = pw, sum = pw;
#pragma unroll
      for (int m = 1; m <= 6; ++m) {
        term *= hh / (float)(m * (m + r));
        sum += term;
      }
      float c = g * ((r == 0) ? 1.f : 2.f) * sum;
      Wr[((size_t)r * COUTP + o) * CINP + i] = (__bf16)c;
      pw *= h / (float)(r + 1);
    }
  }
}

__global__ void setup_all(const float* __restrict__ x,
                          const float* __restrict__ W1, const float* __restrict__ P1,
                          const float* __restrict__ W2, const float* __restrict__ P2,
                          const float* __restrict__ W3, const float* __restrict__ P3,
                          __bf16* __restrict__ Xb, __bf16* __restrict__ Wr1,
                          __bf16* __restrict__ Wr2, __bf16* __restrict__ Wr3,
                          __bf16* __restrict__ Af, float* __restrict__ stats) {
  int blk = blockIdx.x;
  if (blk < 256) { build_wr_body(W1, P1, Wr1, 700, 704, 256, 256, blk); return; }
  blk -= 256;
  if (blk < 256) { build_wr_body(W2, P2, Wr2, 256, 256, 256, 256, blk); return; }
  blk -= 256;
  if (blk < 32) { build_wr_body(W3, P3, Wr3, 256, 256, 20, 32, blk); return; }
  blk -= 32;
  if (blk < 196) {  // Afir (112 x 448): [t][r*100+s] = PHI[s-t+24][r], else 0
    int idx = blk * 256 + threadIdx.x;
    if (idx < 112 * 448) {
      int t = idx / 448, k = idx - t * 448;
      float v = 0.f;
      if (t < 100 && k < 400) {
        int r = k / 100, s = k - r * 100;
        int tau = s - t + 24;
        if (tau >= 0 && tau < 25) v = PHI.v[tau][r];
      }
      Af[idx] = (__bf16)v;
    }
    return;
  }
  blk -= 196;
  if (blk < 12800) {  // x (B,T,700) f32 -> Xb (T,B,704) bf16
    int t = blk >> 7, b = blk & 127;
    const float* src = x + ((size_t)b * T_LEN + t) * 700;
    __bf16* dst = Xb + (size_t)blk * 704;
    for (int c = threadIdx.x; c < 704; c += 256) dst[c] = (c < 700) ? (__bf16)src[c] : (__bf16)0.f;
    return;
  }
  blk -= 12800;
  if (blk == 0) {
    for (int i = threadIdx.x; i < 1024; i += 256) stats[i] = 0.f;
  }
}

// ---------------------------------------------------------------------------
// Main GEMM, BK=64: Z[k=(r,t)][n=(b,o)] = A @ Wr^T. Pure async-DMA staging.
// LDS: [row][64], 8-elem kgroup slot s holds logical group s^(row&7).
// ---------------------------------------------------------------------------
template <int CINP, int BLK_N, int WROWS, int WCOLS, int CO_SH>
__global__ __launch_bounds__(256, 2)
void gemm_rk64(const __bf16* __restrict__ A, const __bf16* __restrict__ Bm,
               __bf16* __restrict__ Z) {
  constexpr int COUTP = 1 << CO_SH;
  constexpr int WM = 128 / WROWS;
  constexpr int WN = BLK_N / WCOLS;
  constexpr int RM = WM / 16;
  constexpr int RN = WN / 16;
  __shared__ __align__(16) __bf16 sA[128 * 64];
  __shared__ __align__(16) __bf16 sB[BLK_N * 64];

  const int tid = threadIdx.x;
  const int w = tid >> 6, lane = tid & 63;
  const int q = lane >> 4, ln = lane & 15;
  const int wrow = w / WCOLS, wcol = w % WCOLS;
  const int srow8 = lane >> 3;
  const int s8 = lane & 7;

  const int t0 = blockIdx.x;
  const int oc = blockIdx.y * BLK_N;
  const __bf16* Abase = A + (size_t)t0 * 128 * CINP;
  const __bf16* Bbase = Bm + (size_t)oc * CINP;

  v4f acc[RM][RN];
#pragma unroll
  for (int a = 0; a < RM; ++a)
#pragma unroll
    for (int b = 0; b < RN; ++b) acc[a][b] = v4f{0.f, 0.f, 0.f, 0.f};

  for (int ic = 0; ic < CINP; ic += 64) {
    for (int j = w; j < 16; j += 4) {  // A: 128 rows, 8 rows/issue
      int m = j * 8 + srow8;
      int g = s8 ^ (m & 7);
      gl_lds16(Abase + (size_t)m * CINP + ic + g * 8, &sA[j * 512]);
    }
    for (int j = w; j < BLK_N / 8; j += 4) {  // B
      int n = j * 8 + srow8;
      int g = s8 ^ (n & 7);
      gl_lds16(Bbase + (size_t)n * CINP + ic + g * 8, &sB[j * 512]);
    }
    __syncthreads();

#pragma unroll
    for (int s = 0; s < 2; ++s) {
      v8bf af[RM], bfr[RN];
#pragma unroll
      for (int a = 0; a < RM; ++a) {
        int m = wrow * WM + a * 16 + ln;
        af[a] = *(const v8bf*)&sA[m * 64 + ((((s << 2) | q) ^ (m & 7)) * 8)];
      }
#pragma unroll
      for (int b = 0; b < RN; ++b) {
        int n = wcol * WN + b * 16 + ln;
        bfr[b] = *(const v8bf*)&sB[n * 64 + ((((s << 2) | q) ^ (n & 7)) * 8)];
      }
#pragma unroll
      for (int a = 0; a < RM; ++a)
#pragma unroll
        for (int b = 0; b < RN; ++b)
          acc[a][b] = __builtin_amdgcn_mfma_f32_16x16x32_bf16(af[a], bfr[b], acc[a][b], 0, 0, 0);
    }
    __syncthreads();
  }

  // C/D: col=lane&15, row=quad*4+reg (m89-verified)
#pragma unroll
  for (int a = 0; a < RM; ++a) {
#pragma unroll
    for (int b = 0; b < RN; ++b) {
      int n = oc + wcol * WN + b * 16 + ln;
      int r = n >> CO_SH, o = n & (COUTP - 1);
#pragma unroll
      for (int rr = 0; rr < 4; ++rr) {
        int m = t0 * 128 + wrow * WM + a * 16 + q * 4 + rr;
        Z[((size_t)r * M_ROWS + m) * COUTP + o] = (__bf16)acc[a][b][rr];
      }
    }
  }
}

// ---------------------------------------------------------------------------
// FIR GEMM, BK=64, K=448: Y(112 x 64-slice) = Afir(112x448) @ Z(448xN).
// B transposed in LDS (k-pair packed b32, [n][35-dword stride]).
// STATS: fused BN sum/sumsq.  SOFTMAX (L3): in-LDS softmax over o + time-sum.
// ---------------------------------------------------------------------------
template <int COUTP, bool STATS, bool SOFTMAX>
__global__ __launch_bounds__(256, 2)
void fir_gemm64(const __bf16* __restrict__ Af, const __bf16* __restrict__ Z,
                __bf16* __restrict__ Yout, float* __restrict__ stats,
                float* __restrict__ outp, int N) {
  __shared__ __align__(16) unsigned char smem[26624];
  __bf16* sA = (__bf16*)smem;               // 112*64*2 = 14336 B
  uint32* sBu = (uint32*)(smem + 14336);    // 64*35*4  =  8960 B

  const int tid = threadIdx.x;
  const int w = tid >> 6, lane = tid & 63;
  const int q = lane >> 4, ln = lane & 15;
  const int srow8 = lane >> 3, s8 = lane & 7;
  const int kp = tid >> 3;    // 0..31
  const int noct = tid & 7;   // 0..7
  const int nb = blockIdx.x * 64;

  v4f acc[7];
#pragma unroll
  for (int a = 0; a < 7; ++a) acc[a] = v4f{0.f, 0.f, 0.f, 0.f};

  for (int kc = 0; kc < K_FIR; kc += 64) {
    for (int j = w; j < 14; j += 4) {  // stage A (112 x 64)
      int m = j * 8 + srow8;
      int g = s8 ^ (m & 7);
      gl_lds16(Af + (size_t)m * K_FIR + kc + g * 8, &sA[j * 512]);
    }
    // stage B transposed
    const __bf16* zp = Z + (size_t)(kc + kp * 2) * N + nb + noct * 8;
    uint4 r0 = *(const uint4*)zp;
    uint4 r1 = *(const uint4*)(zp + N);
    const ushort_t* p0 = (const ushort_t*)&r0;
    const ushort_t* p1 = (const ushort_t*)&r1;
#pragma unroll
    for (int j = 0; j < 8; ++j) {
      uint32 val = (uint32)p0[j] | ((uint32)p1[j] << 16);
      sBu[(noct * 8 + j) * 35 + kp] = val;
    }
    __syncthreads();

#pragma unroll
    for (int s = 0; s < 2; ++s) {
      v8bf af[7];
#pragma unroll
      for (int a = 0; a < 7; ++a) {
        int m = a * 16 + ln;
        af[a] = *(const v8bf*)&sA[m * 64 + ((((s << 2) | q) ^ (m & 7)) * 8)];
      }
      int base = (w * 16 + ln) * 35 + s * 16 + q * 4;
      uint32 tmp[4] = {sBu[base], sBu[base + 1], sBu[base + 2], sBu[base + 3]};
      v8bf bfr = *(const v8bf*)tmp;
#pragma unroll
      for (int a = 0; a < 7; ++a)
        acc[a] = __builtin_amdgcn_mfma_f32_16x16x32_bf16(af[a], bfr, acc[a], 0, 0, 0);
    }
    __syncthreads();
  }

  int ng = nb + w * 16 + ln;
  if (!SOFTMAX) {
    float s = 0.f, ss = 0.f;
#pragma unroll
    for (int a = 0; a < 7; ++a) {
#pragma unroll
      for (int rr = 0; rr < 4; ++rr) {
        int t = a * 16 + q * 4 + rr;
        float v = acc[a][rr];
        if (t < 100) {
          Yout[(size_t)t * N + ng] = (__bf16)v;
          s += v; ss += v * v;
        }
      }
    }
    if (STATS) {
      s += __shfl_xor(s, 16); ss += __shfl_xor(ss, 16);
      s += __shfl_xor(s, 32); ss += __shfl_xor(ss, 32);
      if (q == 0) {
        int o = ng & (COUTP - 1);
        atomicAdd(&stats[o], s);
        atomicAdd(&stats[COUTP + o], ss);
      }
    }
  } else {
    // L3: this block holds all t and all o for 2 batch entries.
    float* smx = (float*)smem;               // [100][65] = 26000 B (reuses sA/sB)
    float* lacc = (float*)(smem + 26000);    // 40 floats
    int col = w * 16 + ln;
#pragma unroll
    for (int a = 0; a < 7; ++a) {
#pragma unroll
      for (int rr = 0; rr < 4; ++rr) {
        int t = a * 16 + q * 4 + rr;
        if (t < 100) smx[t * 65 + col] = acc[a][rr];
      }
    }
    if (tid < 64) lacc[tid & 63] = 0.f;
    __syncthreads();
    if (tid < 200) {
      int bl = tid / 100, t = tid - bl * 100;
      const float* rr = &smx[t * 65 + bl * 32];
      float v[20], m = -1e30f;
#pragma unroll
      for (int o = 0; o < 20; ++o) { v[o] = rr[o]; m = fmaxf(m, v[o]); }
      float sum = 0.f;
#pragma unroll
      for (int o = 0; o < 20; ++o) { v[o] = expf(v[o] - m); sum += v[o]; }
      float inv = 1.f / sum;
#pragma unroll
      for (int o = 0; o < 20; ++o) atomicAdd(&lacc[bl * 20 + o], v[o] * inv);
    }
    __syncthreads();
    if (tid < 40) {
      int bl = tid / 20, o = tid - bl * 20;
      int b = (nb >> 5) + bl;
      outp[b * 20 + o] = lacc[bl * 20 + o];
    }
  }
}

// normalize + relu, bf16x8 vectorized, in-place on Y
__global__ __launch_bounds__(256)
void bn_apply_relu8(__bf16* __restrict__ h, const float* __restrict__ stats,
                    const float* __restrict__ gamma, const float* __restrict__ beta) {
  int idx = blockIdx.x * 256 + threadIdx.x;
  int co = (idx & 31) * 8;
  size_t row = (size_t)(idx >> 5);
  __bf16* p = h + row * 256 + co;
  uint4 raw = *(const uint4*)p;
  const ushort_t* pr = (const ushort_t*)&raw;
  uint4 outv;
  ushort_t* po = (ushort_t*)&outv;
#pragma unroll
  for (int j = 0; j < 8; ++j) {
    int c = co + j;
    float mean = stats[c] * (1.f / 12800.f);
    float var = stats[256 + c] * (1.f / 12800.f) - mean * mean;
    float inv = rsqrtf(var + 1e-5f) * gamma[c];
    uint32 u = (uint32)pr[j] << 16;
    float xv; __builtin_memcpy(&xv, &u, 4);
    float v = (xv - mean) * inv + beta[c];
    v = fmaxf(v, 0.f);
    __bf16 bv = (__bf16)v;
    po[j] = *(const ushort_t*)&bv;
  }
  *(uint4*)p = outv;
}

// ---------------------------------------------------------------------------

extern "C" void kernel_launch(void* const* d_in, const int* in_sizes, int n_in,
                              void* d_out, int out_size, void* d_ws, size_t ws_size,
                              hipStream_t stream) {
  const float* x  = (const float*)d_in[0];
  const float* W1 = (const float*)d_in[1];
  const float* P1 = (const float*)d_in[2];
  const float* W2 = (const float*)d_in[3];
  const float* P2 = (const float*)d_in[4];
  const float* W3 = (const float*)d_in[5];
  const float* P3 = (const float*)d_in[6];
  const float* g1 = (const float*)d_in[7];
  const float* b1 = (const float*)d_in[8];
  const float* g2 = (const float*)d_in[9];
  const float* b2 = (const float*)d_in[10];
  float* out = (float*)d_out;

  constexpr size_t XB_B  = (size_t)M_ROWS * 704 * 2;        // 18,022,400
  constexpr size_t Z_B   = (size_t)K_FIR * 32768 * 2;       // 29,360,128
  constexpr size_t Y12_B = (size_t)M_ROWS * 256 * 2;        //  6,553,600
  constexpr size_t W1_B  = (size_t)R_RANK * 256 * 704 * 2;  //  1,441,792
  constexpr size_t W2_B  = (size_t)R_RANK * 256 * 256 * 2;  //    524,288
  constexpr size_t W3_B  = (size_t)R_RANK * 32 * 256 * 2;   //     65,536
  constexpr size_t AF_B  = (size_t)112 * K_FIR * 2;         //    100,352
  constexpr size_t ST_B  = 4096;
  constexpr size_t TOTAL = XB_B + Z_B + Y12_B + W1_B + W2_B + W3_B + AF_B + ST_B;
  if (ws_size < TOTAL) return;

  char* ws = (char*)d_ws;
  size_t off = 0;
  __bf16* Xb   = (__bf16*)(ws + off); off += XB_B;
  __bf16* Zb   = (__bf16*)(ws + off); off += Z_B;
  __bf16* Yb   = (__bf16*)(ws + off); off += Y12_B;   // Y1 then Y2 (in-place BN)
  __bf16* Wr1  = (__bf16*)(ws + off); off += W1_B;
  __bf16* Wr2  = (__bf16*)(ws + off); off += W2_B;
  __bf16* Wr3  = (__bf16*)(ws + off); off += W3_B;
  __bf16* Afir = (__bf16*)(ws + off); off += AF_B;
  float*  stats1 = (float*)(ws + off);
  float*  stats2 = stats1 + 512;

  // fused setup: 256+256+32+196+12800+1 blocks
  setup_all<<<dim3(13541), 256, 0, stream>>>(x, W1, P1, W2, P2, W3, P3,
                                             Xb, Wr1, Wr2, Wr3, Afir, stats1);

  // layer 1: GEMM (12800 x 1024 x 704), BLK_N=256 -> FIR (+stats) -> BN in-place
  gemm_rk64<704, 256, 2, 2, 8><<<dim3(100, 4), 256, 0, stream>>>(Xb, Wr1, Zb);
  fir_gemm64<256, true, false><<<dim3(512), 256, 0, stream>>>(
      Afir, Zb, Yb, stats1, nullptr, 32768);
  bn_apply_relu8<<<dim3(1600), 256, 0, stream>>>(Yb, stats1, g1, b1);

  // layer 2: GEMM (12800 x 1024 x 256), BLK_N=256
  gemm_rk64<256, 256, 2, 2, 8><<<dim3(100, 4), 256, 0, stream>>>(Yb, Wr2, Zb);
  fir_gemm64<256, true, false><<<dim3(512), 256, 0, stream>>>(
      Afir, Zb, Yb, stats2, nullptr, 32768);
  bn_apply_relu8<<<dim3(1600), 256, 0, stream>>>(Yb, stats2, g2, b2);

  // layer 3: GEMM (12800 x 128 x 256), then FIR + fused softmax/time-sum
  gemm_rk64<256, 64, 2, 2, 5><<<dim3(100, 2), 256, 0, stream>>>(Yb, Wr3, Zb);
  fir_gemm64<32, false, true><<<dim3(64), 256, 0, stream>>>(
      Afir, Zb, nullptr, nullptr, out, 4096);
}